// Round 2
// baseline (870.907 us; speedup 1.0000x reference)
//
#include <hip/hip_runtime.h>

#define MROWS 8192
#define NCOLS 128
#define SPLITK 8

using f32x4  = __attribute__((ext_vector_type(4))) float;
using bf16x8 = __attribute__((ext_vector_type(8))) short;
using u32x4  = __attribute__((ext_vector_type(4))) unsigned int;
using u32x2  = __attribute__((ext_vector_type(2))) unsigned int;

__device__ __forceinline__ unsigned short f2bf(float f) {
    unsigned int u = __float_as_uint(f);
    u += 0x7fffu + ((u >> 16) & 1u);   // RNE
    return (unsigned short)(u >> 16);
}
__device__ __forceinline__ unsigned int pk2(float a, float b) {
    return (unsigned int)f2bf(a) | ((unsigned int)f2bf(b) << 16);
}

// C[M,128] = A[M,Kdim](fp32) @ B[Kdim,128], B stored transposed bf16 Bt[c][k].
// No LDS, no barriers: each lane loads its MFMA fragments directly from
// global (A: 32B fp32 -> cvt bf16; B: 16B bf16, L2-resident) with a manual
// register double-buffer so HBM requests stay in flight continuously.
// OUTMODE: 0 = fp32 partials transposed  Pt[s][c][r]   (float4 stores)
//          1 = fp32 partials row-major   P[s][r][c]    (scalar stores, 64B segs)
//          2 = bf16 direct transposed    Tt[c][r]      (single split only)
template <int OUTMODE>
__global__ __launch_bounds__(256, 2) void gemm_direct(
    const float* __restrict__ A,
    const unsigned short* __restrict__ Bt,
    void* __restrict__ out,
    int Kdim, int KC, int ldb)
{
    const int tid  = threadIdx.x;
    const int wave = tid >> 6;
    const int lane = tid & 63;
    const int lrow = lane & 15;
    const int lq   = lane >> 4;          // quad 0..3
    const int mq   = (wave & 1) * 64;
    const int nq   = (wave >> 1) * 64;
    const int m0   = blockIdx.x * 128;
    const int s    = blockIdx.y;
    const int kbase = s * KC;

    const float*          Arow[4];
    const unsigned short* Brow[4];
#pragma unroll
    for (int mt = 0; mt < 4; ++mt)
        Arow[mt] = A + (size_t)(m0 + mq + mt * 16 + lrow) * Kdim + kbase + lq * 8;
#pragma unroll
    for (int nt = 0; nt < 4; ++nt)
        Brow[nt] = Bt + (size_t)(nq + nt * 16 + lrow) * ldb + kbase + lq * 8;

    f32x4 acc[4][4];
#pragma unroll
    for (int i = 0; i < 4; ++i)
#pragma unroll
        for (int j = 0; j < 4; ++j)
            acc[i][j] = {0.f, 0.f, 0.f, 0.f};

    // double-buffered fragment registers
    f32x4 a0[2][4], a1[2][4];
    u32x4 bv[2][4];

    auto load_frag = [&](int buf, int k) {
#pragma unroll
        for (int mt = 0; mt < 4; ++mt) {
            a0[buf][mt] = *(const f32x4*)(Arow[mt] + k);
            a1[buf][mt] = *(const f32x4*)(Arow[mt] + k + 4);
        }
#pragma unroll
        for (int nt = 0; nt < 4; ++nt)
            bv[buf][nt] = *(const u32x4*)(Brow[nt] + k);
    };

    load_frag(0, 0);
    int cur = 0;
    for (int k = 0; k < KC; k += 32) {
        const int kn = (k + 32 < KC) ? k + 32 : k;   // last iter: harmless reload
        load_frag(cur ^ 1, kn);                      // prefetch next K-step

        bf16x8 af[4], bf[4];
#pragma unroll
        for (int mt = 0; mt < 4; ++mt) {
            u32x4 av;
            av.x = pk2(a0[cur][mt].x, a0[cur][mt].y);
            av.y = pk2(a0[cur][mt].z, a0[cur][mt].w);
            av.z = pk2(a1[cur][mt].x, a1[cur][mt].y);
            av.w = pk2(a1[cur][mt].z, a1[cur][mt].w);
            af[mt] = __builtin_bit_cast(bf16x8, av);
            bf[mt] = __builtin_bit_cast(bf16x8, bv[cur][mt]);
        }
#pragma unroll
        for (int mt = 0; mt < 4; ++mt)
#pragma unroll
            for (int nt = 0; nt < 4; ++nt)
                acc[mt][nt] = __builtin_amdgcn_mfma_f32_16x16x32_bf16(
                    af[mt], bf[nt], acc[mt][nt], 0, 0, 0);
        cur ^= 1;
    }

    if (OUTMODE == 0) {
        float* P = (float*)out + (size_t)s * (MROWS * NCOLS);
#pragma unroll
        for (int mt = 0; mt < 4; ++mt) {
            int r = m0 + mq + mt * 16 + lq * 4;
#pragma unroll
            for (int nt = 0; nt < 4; ++nt) {
                int c = nq + nt * 16 + lrow;
                *(f32x4*)&P[(size_t)c * MROWS + r] = acc[mt][nt];
            }
        }
    } else if (OUTMODE == 1) {
        float* P = (float*)out + (size_t)s * (MROWS * NCOLS);
#pragma unroll
        for (int mt = 0; mt < 4; ++mt) {
            int r = m0 + mq + mt * 16 + lq * 4;
#pragma unroll
            for (int nt = 0; nt < 4; ++nt) {
                int c = nq + nt * 16 + lrow;
#pragma unroll
                for (int e = 0; e < 4; ++e)
                    P[(size_t)(r + e) * NCOLS + c] = acc[mt][nt][e];
            }
        }
    } else {
        unsigned short* Tt = (unsigned short*)out;
#pragma unroll
        for (int mt = 0; mt < 4; ++mt) {
            int r = m0 + mq + mt * 16 + lq * 4;
#pragma unroll
            for (int nt = 0; nt < 4; ++nt) {
                int c = nq + nt * 16 + lrow;
                u32x2 v;
                v.x = pk2(acc[mt][nt][0], acc[mt][nt][1]);
                v.y = pk2(acc[mt][nt][2], acc[mt][nt][3]);
                *(u32x2*)&Tt[(size_t)c * MROWS + r] = v;
            }
        }
    }
}

// Wt[c][k] = bf16(W[k][c]) : 256x128 fp32 -> transposed bf16
__global__ void convert_w(const float* __restrict__ W, unsigned short* __restrict__ Wt) {
    int idx = blockIdx.x * 256 + threadIdx.x;   // 32768 total
    int k = idx >> 7, c = idx & 127;
    Wt[c * 256 + k] = f2bf(W[idx]);
}

// Rt[c][r] = bf16( filt[r] * sum_s Pt[s][c][r] )
__global__ void reduce2(const float* __restrict__ P, const float* __restrict__ filt,
                        unsigned short* __restrict__ Rt) {
    int idx4 = (blockIdx.x * 256 + threadIdx.x) * 4;
    f32x4 sum = {0.f, 0.f, 0.f, 0.f};
#pragma unroll
    for (int s = 0; s < SPLITK; ++s)
        sum += *(const f32x4*)&P[(size_t)s * (MROWS * NCOLS) + idx4];
    int r = idx4 & (MROWS - 1);
    f32x4 fl = *(const f32x4*)&filt[r];
    sum *= fl;
    u32x2 v;
    v.x = pk2(sum.x, sum.y);
    v.y = pk2(sum.z, sum.w);
    *(u32x2*)&Rt[idx4] = v;
}

// out[r][c] = sum_s P[s][r][c]   (row-major partials, fully coalesced)
__global__ void reduce3(const float* __restrict__ P, float* __restrict__ outp) {
    int idx4 = (blockIdx.x * 256 + threadIdx.x) * 4;
    f32x4 sum = {0.f, 0.f, 0.f, 0.f};
#pragma unroll
    for (int s = 0; s < SPLITK; ++s)
        sum += *(const f32x4*)&P[(size_t)s * (MROWS * NCOLS) + idx4];
    *(f32x4*)&outp[idx4] = sum;
}

extern "C" void kernel_launch(void* const* d_in, const int* in_sizes, int n_in,
                              void* d_out, int out_size, void* d_ws, size_t ws_size,
                              hipStream_t stream) {
    const float* features     = (const float*)d_in[0];
    const float* wavelets     = (const float*)d_in[1];
    const float* wavelets_inv = (const float*)d_in[2];
    const float* W            = (const float*)d_in[3];
    const float* filt         = (const float*)d_in[4];
    float* outp = (float*)d_out;

    char* ws = (char*)d_ws;
    float*          P  = (float*)ws;                                        // 32 MB partials
    unsigned short* Tt = (unsigned short*)(ws + (size_t)32 * 1024 * 1024);  // 2 MB  Tt[c][r]
    unsigned short* Rt = (unsigned short*)(ws + (size_t)34 * 1024 * 1024);  // 2 MB  Rt[c][r]
    unsigned short* Wt = (unsigned short*)(ws + (size_t)36 * 1024 * 1024);  // 64 KB Wt[c][k]

    // 1) W -> Wt (bf16, transposed)
    convert_w<<<128, 256, 0, stream>>>(W, Wt);
    // 2) Tt = (features @ W)^T   (K=256, direct bf16 transposed output)
    gemm_direct<2><<<dim3(64, 1), 256, 0, stream>>>(features, Wt, (void*)Tt, 256, 256, 256);
    // 3) Pt[s] = partial (wavelets_inv @ T)^T   (split-K=8)
    gemm_direct<0><<<dim3(64, 8), 256, 0, stream>>>(wavelets_inv, Tt, (void*)P, 8192, 1024, 8192);
    // 4) Rt = bf16(filt ⊙ reduce(Pt))  (transposed)
    reduce2<<<1024, 256, 0, stream>>>(P, filt, Rt);
    // 5) P[s] = partial wavelets @ R   (row-major partials)
    gemm_direct<1><<<dim3(64, 8), 256, 0, stream>>>(wavelets, Rt, (void*)P, 8192, 1024, 8192);
    // 6) out = reduce(P)
    reduce3<<<1024, 256, 0, stream>>>(P, outp);
}